// Round 3
// baseline (3613.853 us; speedup 1.0000x reference)
//
#include <hip/hip_runtime.h>
#include <math.h>

typedef _Float16 f16;
typedef _Float16 f16x8 __attribute__((ext_vector_type(8)));
typedef float f32x4 __attribute__((ext_vector_type(4)));

// Problem dims
#define T_ 1024
#define B_ 128
#define DI_ 256
#define DL_ 512
#define V_ 10000

// ws layout (bytes)
#define OFF_EMBH   0u          // V*DI fp16 = 5,120,000
#define OFF_WIT    5120000u    // [512][256] fp16 = 262,144   (WiT[n][k] = Wi[k][n])
#define OFF_WHT    5382144u    // [512][512] fp16 = 524,288   (WhT[n][k] = Wh[k][n])
#define OFF_BSUM   5906432u    // 512 f32 = 2048              (bi + bh)
#define OFF_FLAGS  5908480u    // 32 int

// ---------------- prep kernels ----------------
__global__ void prep_emb_k(const float* __restrict__ emb, f16* __restrict__ embH, int n) {
  for (int i = blockIdx.x * blockDim.x + threadIdx.x; i < n; i += gridDim.x * blockDim.x)
    embH[i] = (f16)emb[i];
}

__global__ void prep_w_k(const float* __restrict__ Wi, const float* __restrict__ Wh,
                         const float* __restrict__ bi, const float* __restrict__ bh,
                         f16* __restrict__ WiT, f16* __restrict__ WhT,
                         float* __restrict__ bsum) {
  int i = blockIdx.x * blockDim.x + threadIdx.x;
  if (i < 131072) {                    // WiT[n][k] = Wi[k][n], k<256, n<512
    int n = i & 511, k = i >> 9;
    WiT[n * 256 + k] = (f16)Wi[k * 512 + n];
  } else if (i < 131072 + 262144) {    // WhT[n][k] = Wh[k][n], k<512, n<512
    int s = i - 131072;
    int n = s & 511, k = s >> 9;
    WhT[n * 512 + k] = (f16)Wh[k * 512 + n];
  } else if (i < 131072 + 262144 + 512) {
    int s = i - 131072 - 262144;
    bsum[s] = bi[s] + bh[s];
  }
}

// ---------------- phase A: PRE = gather(embH, X) @ Wi + (bi+bh) ----------------
// M=131072 (t*128+b), N=512, K=256. 128x128 tile / WG, 4 waves, 16x16x32 fp16 MFMA.
__global__ __launch_bounds__(256) void gemmA_k(
    const int* __restrict__ X, const f16* __restrict__ embH,
    const f16* __restrict__ WiT, const float* __restrict__ bsum,
    float* __restrict__ out) {
  __shared__ f16 Ah[128][40];   // [m][k] pad 32->40
  __shared__ f16 Bh[128][40];   // [n][k]
  __shared__ int idxL[128];

  int tid = threadIdx.x;
  int lane = tid & 63, w = tid >> 6;
  int wr = w >> 1, wc = w & 1;
  int m0 = blockIdx.y * 128, n0 = blockIdx.x * 128;

  if (tid < 128) {
    int v = X[m0 + tid];                      // int32 input (harness stores int as int32)
    idxL[tid] = (v < 0) ? 0 : ((v >= V_) ? (V_ - 1) : v);  // clamp: fault -> finite error
  }
  __syncthreads();

  f32x4 acc[4][4];
#pragma unroll
  for (int i = 0; i < 4; i++)
#pragma unroll
    for (int jj = 0; jj < 4; jj++) acc[i][jj] = (f32x4){0.f, 0.f, 0.f, 0.f};

  int ar = lane & 15, koff = (lane >> 4) * 8;

  for (int kk = 0; kk < 8; kk++) {
    int k0 = kk * 32;
#pragma unroll
    for (int q = 0; q < 2; q++) {
      int s = tid + 256 * q;            // 0..511
      int row = s >> 2, part = s & 3;   // 4 x 16B per 32-f16 row chunk
      *(uint4*)&Ah[row][part * 8] = *(const uint4*)&embH[idxL[row] * 256 + k0 + part * 8];
      *(uint4*)&Bh[row][part * 8] = *(const uint4*)&WiT[(n0 + row) * 256 + k0 + part * 8];
    }
    __syncthreads();
    f16x8 a[4], b[4];
#pragma unroll
    for (int i = 0; i < 4; i++) a[i] = *(const f16x8*)&Ah[wr * 64 + i * 16 + ar][koff];
#pragma unroll
    for (int jj = 0; jj < 4; jj++) b[jj] = *(const f16x8*)&Bh[wc * 64 + jj * 16 + ar][koff];
#pragma unroll
    for (int i = 0; i < 4; i++)
#pragma unroll
      for (int jj = 0; jj < 4; jj++)
        acc[i][jj] = __builtin_amdgcn_mfma_f32_16x16x32_f16(a[i], b[jj], acc[i][jj], 0, 0, 0);
    __syncthreads();
  }

  int r0 = (lane >> 4) * 4;
#pragma unroll
  for (int i = 0; i < 4; i++) {
#pragma unroll
    for (int jj = 0; jj < 4; jj++) {
      int gm = m0 + wr * 64 + i * 16 + r0;
      int gn = n0 + wc * 64 + jj * 16 + ar;
      float bs = bsum[gn];
#pragma unroll
      for (int r = 0; r < 4; r++)
        out[(size_t)(gm + r) * 512 + gn] = acc[i][jj][r] + bs;
    }
  }
}

// ---------------- phase B: persistent recurrence ----------------
// 32 WGs = 8 clusters (16 batch rows each) x 4 WGs (128-col slice of Wh^T in LDS).
// h exchange through d_out (H[t]); flag counters, agent-scope release/acquire.
// bids {c, c+8, c+16, c+24} share bid%8 -> same XCD (round-robin dispatch): intra-XCD exchange.
__global__ __launch_bounds__(256, 1) void rnnB_k(
    const float* __restrict__ h0, const f16* __restrict__ WhT,
    float* __restrict__ H, int* flags) {
  __shared__ f16 WhL[128][520];  // [local n][k] pad 512->520 (133,120 B)
  __shared__ f16 hL[16][520];    // [batch row][k]            ( 16,640 B)

  int tid = threadIdx.x, lane = tid & 63, w = tid >> 6;
  int bid = blockIdx.x;
  int c = bid & 7;    // cluster (batch slice)
  int j = bid >> 3;   // N-slice within cluster
  int b0 = c * 16, n0 = j * 128;

  // load Wh^T slice into LDS once: rows n0..n0+127, k 0..511
  for (int s = tid; s < 128 * 64; s += 256) {
    int r = s >> 6, part = s & 63;
    *(uint4*)&WhL[r][part * 8] = *(const uint4*)&WhT[(size_t)(n0 + r) * 512 + part * 8];
  }

  int ar = lane & 15, koff = (lane >> 4) * 8;
  int r0 = (lane >> 4) * 4;

  for (int t = 0; t < 1024; t++) {
    float* Ht = H + (size_t)t * (B_ * DL_);

    // prefetch PRE[t] for this lane's outputs (independent of siblings; hides HBM latency)
    int gcol0 = n0 + w * 32 + ar;
    float pre[2][4];
#pragma unroll
    for (int jj = 0; jj < 2; jj++)
#pragma unroll
      for (int r = 0; r < 4; r++)
        pre[jj][r] = Ht[(size_t)(b0 + r0 + r) * 512 + gcol0 + jj * 16];

    // wait for siblings to have published h_{t-1}
    if (t > 0 && tid < 4 && tid != j) {
      while (__hip_atomic_load(&flags[c * 4 + tid], __ATOMIC_ACQUIRE,
                               __HIP_MEMORY_SCOPE_AGENT) < t) {
      }
    }
    __syncthreads();

    // stage h_{t-1} (16 x 512 f32 -> fp16 LDS)
    const float4* hs = (const float4*)((t == 0) ? (h0 + b0 * 512)
                                                : (H + (size_t)(t - 1) * (B_ * DL_) + b0 * 512));
#pragma unroll
    for (int q = 0; q < 8; q++) {
      int s = tid + 256 * q;          // 0..2047 float4s
      float4 v = hs[s];
      int row = s >> 7, k4 = (s & 127) * 4;
      hL[row][k4 + 0] = (f16)v.x;
      hL[row][k4 + 1] = (f16)v.y;
      hL[row][k4 + 2] = (f16)v.z;
      hL[row][k4 + 3] = (f16)v.w;
    }
    __syncthreads();

    // [16 x 128] = hL[16,512] @ WhL[512,128]  (wave w: 32 cols)
    f32x4 acc0 = {0.f, 0.f, 0.f, 0.f}, acc1 = {0.f, 0.f, 0.f, 0.f};
#pragma unroll
    for (int kk = 0; kk < 16; kk++) {
      f16x8 a = *(const f16x8*)&hL[ar][kk * 32 + koff];
      f16x8 bv0 = *(const f16x8*)&WhL[w * 32 + ar][kk * 32 + koff];
      f16x8 bv1 = *(const f16x8*)&WhL[w * 32 + 16 + ar][kk * 32 + koff];
      acc0 = __builtin_amdgcn_mfma_f32_16x16x32_f16(a, bv0, acc0, 0, 0, 0);
      acc1 = __builtin_amdgcn_mfma_f32_16x16x32_f16(a, bv1, acc1, 0, 0, 0);
    }

    // epilogue: h = tanh(PRE + acc); overwrite H[t] (also the exchange medium)
#pragma unroll
    for (int jj = 0; jj < 2; jj++) {
      f32x4 acc = jj ? acc1 : acc0;
#pragma unroll
      for (int r = 0; r < 4; r++) {
        size_t o = (size_t)(b0 + r0 + r) * 512 + gcol0 + jj * 16;
        Ht[o] = tanhf(acc[r] + pre[jj][r]);
      }
    }

    __syncthreads();  // drains vmcnt(0) before s_barrier -> all h stores done
    if (tid == 0)
      __hip_atomic_store(&flags[c * 4 + j], t + 1, __ATOMIC_RELEASE,
                         __HIP_MEMORY_SCOPE_AGENT);
  }
}

// ---------------- launch ----------------
extern "C" void kernel_launch(void* const* d_in, const int* in_sizes, int n_in,
                              void* d_out, int out_size, void* d_ws, size_t ws_size,
                              hipStream_t stream) {
  const int* X     = (const int*)d_in[0];     // int32 (harness stores integer inputs as int32)
  const float* h0  = (const float*)d_in[1];
  const float* emb = (const float*)d_in[2];
  const float* Wi  = (const float*)d_in[3];
  const float* bi  = (const float*)d_in[4];
  const float* Wh  = (const float*)d_in[5];
  const float* bh  = (const float*)d_in[6];
  float* H = (float*)d_out;

  char* ws = (char*)d_ws;
  f16* embH   = (f16*)(ws + OFF_EMBH);
  f16* WiT    = (f16*)(ws + OFF_WIT);
  f16* WhT    = (f16*)(ws + OFF_WHT);
  float* bsum = (float*)(ws + OFF_BSUM);
  int* flags  = (int*)(ws + OFF_FLAGS);

  hipMemsetAsync(flags, 0, 32 * sizeof(int), stream);
  prep_emb_k<<<2560, 256, 0, stream>>>(emb, embH, V_ * DI_);
  prep_w_k<<<1538, 256, 0, stream>>>(Wi, Wh, bi, bh, WiT, WhT, bsum);
  gemmA_k<<<dim3(4, 1024), 256, 0, stream>>>(X, embH, WiT, bsum, H);
  rnnB_k<<<32, 256, 0, stream>>>(h0, WhT, H, flags);
}

// Round 4
// 3352.014 us; speedup vs baseline: 1.0781x; 1.0781x over previous
//
#include <hip/hip_runtime.h>
#include <math.h>

typedef _Float16 f16;
typedef _Float16 f16x8 __attribute__((ext_vector_type(8)));
typedef float f32x4 __attribute__((ext_vector_type(4)));

// Problem dims
#define T_ 1024
#define B_ 128
#define DI_ 256
#define DL_ 512
#define V_ 10000

// ws layout (bytes)
#define OFF_EMBH   0u          // V*DI fp16 = 5,120,000
#define OFF_WIT    5120000u    // [512][256] fp16 = 262,144
#define OFF_WHT    5382144u    // [512][512] fp16 = 524,288
#define OFF_BSUM   5906432u    // 512 f32 = 2048
#define OFF_FLAGS  5908480u    // 32 int = 128
#define OFF_XBUF   5908608u    // 2 slots x 8 clusters x 16 x 512 fp16 = 262,144

// fast tanh: 1 - 2/(exp(2x)+1), via v_exp_f32 + v_rcp_f32 (~1e-6 abs err, fine vs 2e-2)
__device__ __forceinline__ float fast_tanh(float x) {
  float xx = fminf(fmaxf(x, -10.f), 10.f);
  float e = __builtin_amdgcn_exp2f(xx * 2.88539008177793f);  // exp(2x)
  return 1.f - 2.f * __builtin_amdgcn_rcpf(e + 1.f);
}

// ---------------- prep kernels ----------------
__global__ void prep_emb_k(const float* __restrict__ emb, f16* __restrict__ embH, int n) {
  for (int i = blockIdx.x * blockDim.x + threadIdx.x; i < n; i += gridDim.x * blockDim.x)
    embH[i] = (f16)emb[i];
}

__global__ void prep_w_k(const float* __restrict__ Wi, const float* __restrict__ Wh,
                         const float* __restrict__ bi, const float* __restrict__ bh,
                         f16* __restrict__ WiT, f16* __restrict__ WhT,
                         float* __restrict__ bsum) {
  int i = blockIdx.x * blockDim.x + threadIdx.x;
  if (i < 131072) {                    // WiT[n][k] = Wi[k][n]
    int n = i & 511, k = i >> 9;
    WiT[n * 256 + k] = (f16)Wi[k * 512 + n];
  } else if (i < 131072 + 262144) {    // WhT[n][k] = Wh[k][n]
    int s = i - 131072;
    int n = s & 511, k = s >> 9;
    WhT[n * 512 + k] = (f16)Wh[k * 512 + n];
  } else if (i < 131072 + 262144 + 512) {
    int s = i - 131072 - 262144;
    bsum[s] = bi[s] + bh[s];
  }
}

// ---------------- phase A: PRE = gather(embH, X) @ Wi + (bi+bh) ----------------
__global__ __launch_bounds__(256) void gemmA_k(
    const int* __restrict__ X, const f16* __restrict__ embH,
    const f16* __restrict__ WiT, const float* __restrict__ bsum,
    float* __restrict__ out) {
  __shared__ f16 Ah[128][40];
  __shared__ f16 Bh[128][40];
  __shared__ int idxL[128];

  int tid = threadIdx.x;
  int lane = tid & 63, w = tid >> 6;
  int wr = w >> 1, wc = w & 1;
  int m0 = blockIdx.y * 128, n0 = blockIdx.x * 128;

  if (tid < 128) {
    int v = X[m0 + tid];
    idxL[tid] = (v < 0) ? 0 : ((v >= V_) ? (V_ - 1) : v);
  }
  __syncthreads();

  f32x4 acc[4][4];
#pragma unroll
  for (int i = 0; i < 4; i++)
#pragma unroll
    for (int jj = 0; jj < 4; jj++) acc[i][jj] = (f32x4){0.f, 0.f, 0.f, 0.f};

  int ar = lane & 15, koff = (lane >> 4) * 8;

  for (int kk = 0; kk < 8; kk++) {
    int k0 = kk * 32;
#pragma unroll
    for (int q = 0; q < 2; q++) {
      int s = tid + 256 * q;
      int row = s >> 2, part = s & 3;
      *(uint4*)&Ah[row][part * 8] = *(const uint4*)&embH[idxL[row] * 256 + k0 + part * 8];
      *(uint4*)&Bh[row][part * 8] = *(const uint4*)&WiT[(n0 + row) * 256 + k0 + part * 8];
    }
    __syncthreads();
    f16x8 a[4], b[4];
#pragma unroll
    for (int i = 0; i < 4; i++) a[i] = *(const f16x8*)&Ah[wr * 64 + i * 16 + ar][koff];
#pragma unroll
    for (int jj = 0; jj < 4; jj++) b[jj] = *(const f16x8*)&Bh[wc * 64 + jj * 16 + ar][koff];
#pragma unroll
    for (int i = 0; i < 4; i++)
#pragma unroll
      for (int jj = 0; jj < 4; jj++)
        acc[i][jj] = __builtin_amdgcn_mfma_f32_16x16x32_f16(a[i], b[jj], acc[i][jj], 0, 0, 0);
    __syncthreads();
  }

  int r0 = (lane >> 4) * 4;
#pragma unroll
  for (int i = 0; i < 4; i++) {
#pragma unroll
    for (int jj = 0; jj < 4; jj++) {
      int gm = m0 + wr * 64 + i * 16 + r0;
      int gn = n0 + wc * 64 + jj * 16 + ar;
      float bs = bsum[gn];
#pragma unroll
      for (int r = 0; r < 4; r++)
        out[(size_t)(gm + r) * 512 + gn] = acc[i][jj][r] + bs;
    }
  }
}

// ---------------- phase B: persistent recurrence ----------------
// 32 WGs = 8 clusters x 4 N-slice WGs. Exchange h (fp16) through a small
// double-buffered MALL-coherent xbuf using explicit sc0 sc1 (system-coherent,
// cache-bypassing) loads/stores — no L2 invalidate/writeback storms, correct
// regardless of WG->XCD placement. Flags: relaxed system-scope atomics;
// ordering via s_waitcnt vmcnt(0) before the flag store (stores are
// write-through, so ack == visible at MALL).
__global__ __launch_bounds__(256, 1) void rnnB_k(
    const float* __restrict__ h0, const f16* __restrict__ WhT,
    float* __restrict__ H, int* flags, f16* xbuf) {
  __shared__ f16 WhL[128][520];  // [local n][k] 133,120 B
  __shared__ f16 hL[16][520];    // [batch row][k] 16,640 B

  int tid = threadIdx.x, lane = tid & 63, w = tid >> 6;
  int bid = blockIdx.x;
  int c = bid & 7;    // cluster (batch slice)
  int j = bid >> 3;   // N-slice within cluster
  int b0 = c * 16, n0 = j * 128;

  // load Wh^T slice into LDS once
  for (int s = tid; s < 128 * 64; s += 256) {
    int r = s >> 6, part = s & 63;
    *(uint4*)&WhL[r][part * 8] = *(const uint4*)&WhT[(size_t)(n0 + r) * 512 + part * 8];
  }

  int ar = lane & 15, koff = (lane >> 4) * 8;
  int r0 = (lane >> 4) * 4;
  int gcol0 = n0 + w * 32 + ar;

  // reader staging coords: thread loads 16B per sibling block
  int srow = tid >> 4, spart = tid & 15;
  int sb[3];
  { int q = 0; for (int bb = 0; bb < 4; bb++) if (bb != j) sb[q++] = bb; }

  for (int t = 0; t < 1024; t++) {
    float* Ht = H + (size_t)t * (B_ * DL_);

    // 1. prefetch PRE[t] (plain cached loads; overlaps the poll+exchange below)
    float pre[2][4];
#pragma unroll
    for (int jj = 0; jj < 2; jj++)
#pragma unroll
      for (int r = 0; r < 4; r++)
        pre[jj][r] = Ht[(size_t)(b0 + r0 + r) * 512 + gcol0 + jj * 16];

    if (t > 0) {
      // 2. poll sibling flags (relaxed system-scope: plain sc0 sc1 loads, no cache maintenance)
#pragma unroll
      for (int s = 0; s < 3; s++) {
        const int* fp = &flags[c * 4 + sb[s]];
        int spin = 0;
        while (__hip_atomic_load(fp, __ATOMIC_RELAXED, __HIP_MEMORY_SCOPE_SYSTEM) < t) {
          if (++spin > (1 << 26)) break;  // fail-safe: finite wrong answer beats a hang
        }
      }
      asm volatile("" ::: "memory");

      // 3. load 3 sibling h slices (16B/thread/block) from MALL
      const f16* xb = xbuf + ((size_t)((t - 1) & 1) * 8 + c) * (16 * 512);
      const f16* base = xb + srow * 512;
      const f16* p0 = base + sb[0] * 128 + spart * 8;
      const f16* p1 = base + sb[1] * 128 + spart * 8;
      const f16* p2 = base + sb[2] * 128 + spart * 8;
      uint4 v0, v1, v2;
      asm volatile("global_load_dwordx4 %0, %1, off sc0 sc1" : "=v"(v0) : "v"(p0) : "memory");
      asm volatile("global_load_dwordx4 %0, %1, off sc0 sc1" : "=v"(v1) : "v"(p1) : "memory");
      asm volatile("global_load_dwordx4 %0, %1, off sc0 sc1" : "=v"(v2) : "v"(p2) : "memory");
      asm volatile("s_waitcnt vmcnt(0)" ::: "memory");
      __builtin_amdgcn_sched_barrier(0);
      *(uint4*)&hL[srow][sb[0] * 128 + spart * 8] = v0;
      *(uint4*)&hL[srow][sb[1] * 128 + spart * 8] = v1;
      *(uint4*)&hL[srow][sb[2] * 128 + spart * 8] = v2;
    } else {
      // t==0: every WG stages the full h0 slice itself (no exchange)
#pragma unroll
      for (int q = 0; q < 8; q++) {
        int s = tid + 256 * q;
        float4 v = ((const float4*)(h0 + b0 * 512))[s];
        int row = s >> 7, k4 = (s & 127) * 4;
        hL[row][k4 + 0] = (f16)v.x;
        hL[row][k4 + 1] = (f16)v.y;
        hL[row][k4 + 2] = (f16)v.z;
        hL[row][k4 + 3] = (f16)v.w;
      }
    }
    __syncthreads();

    // 4. [16 x 128] = hL[16,512] @ WhL[512,128]
    f32x4 acc0 = {0.f, 0.f, 0.f, 0.f}, acc1 = {0.f, 0.f, 0.f, 0.f};
#pragma unroll
    for (int kk = 0; kk < 16; kk++) {
      f16x8 a = *(const f16x8*)&hL[ar][kk * 32 + koff];
      f16x8 bv0 = *(const f16x8*)&WhL[w * 32 + ar][kk * 32 + koff];
      f16x8 bv1 = *(const f16x8*)&WhL[w * 32 + 16 + ar][kk * 32 + koff];
      acc0 = __builtin_amdgcn_mfma_f32_16x16x32_f16(a, bv0, acc0, 0, 0, 0);
      acc1 = __builtin_amdgcn_mfma_f32_16x16x32_f16(a, bv1, acc1, 0, 0, 0);
    }

    // 5. h = tanh(PRE + acc)
    float hf[2][4];
    f16 hv[2][4];
#pragma unroll
    for (int jj = 0; jj < 2; jj++) {
      f32x4 acc = jj ? acc1 : acc0;
#pragma unroll
      for (int r = 0; r < 4; r++) {
        hf[jj][r] = fast_tanh(acc[r] + pre[jj][r]);
        hv[jj][r] = (f16)hf[jj][r];
      }
    }

    // 6. publish own fp16 slice to xbuf slot t&1 (write-through to MALL)
    f16* xw = xbuf + ((size_t)(t & 1) * 8 + c) * (16 * 512);
#pragma unroll
    for (int jj = 0; jj < 2; jj++)
#pragma unroll
      for (int r = 0; r < 4; r++) {
        const f16* dst = xw + (r0 + r) * 512 + gcol0 + jj * 16;
        int ui = (int)__builtin_bit_cast(unsigned short, hv[jj][r]);
        asm volatile("global_store_short %0, %1, off sc0 sc1" :: "v"(dst), "v"(ui) : "memory");
      }

    // 7. output H[t] (plain cached; nobody reads it cross-WG)
#pragma unroll
    for (int jj = 0; jj < 2; jj++)
#pragma unroll
      for (int r = 0; r < 4; r++)
        Ht[(size_t)(b0 + r0 + r) * 512 + gcol0 + jj * 16] = hf[jj][r];

    // 8. drain stores (sc1 ack == at MALL), all-wave barrier, then release flag
    asm volatile("s_waitcnt vmcnt(0)" ::: "memory");
    __syncthreads();

    // 9. own slice straight into LDS for step t+1 (disjoint from siblings' regions)
#pragma unroll
    for (int jj = 0; jj < 2; jj++)
#pragma unroll
      for (int r = 0; r < 4; r++)
        hL[r0 + r][gcol0 + jj * 16] = hv[jj][r];

    if (tid == 0)
      __hip_atomic_store(&flags[c * 4 + j], t + 1, __ATOMIC_RELAXED,
                         __HIP_MEMORY_SCOPE_SYSTEM);
  }
}

// ---------------- launch ----------------
extern "C" void kernel_launch(void* const* d_in, const int* in_sizes, int n_in,
                              void* d_out, int out_size, void* d_ws, size_t ws_size,
                              hipStream_t stream) {
  const int* X     = (const int*)d_in[0];
  const float* h0  = (const float*)d_in[1];
  const float* emb = (const float*)d_in[2];
  const float* Wi  = (const float*)d_in[3];
  const float* bi  = (const float*)d_in[4];
  const float* Wh  = (const float*)d_in[5];
  const float* bh  = (const float*)d_in[6];
  float* H = (float*)d_out;

  char* ws = (char*)d_ws;
  f16* embH   = (f16*)(ws + OFF_EMBH);
  f16* WiT    = (f16*)(ws + OFF_WIT);
  f16* WhT    = (f16*)(ws + OFF_WHT);
  float* bsum = (float*)(ws + OFF_BSUM);
  int* flags  = (int*)(ws + OFF_FLAGS);
  f16* xbuf   = (f16*)(ws + OFF_XBUF);

  hipMemsetAsync(flags, 0, 32 * sizeof(int), stream);
  prep_emb_k<<<2560, 256, 0, stream>>>(emb, embH, V_ * DI_);
  prep_w_k<<<1538, 256, 0, stream>>>(Wi, Wh, bi, bh, WiT, WhT, bsum);
  gemmA_k<<<dim3(4, 1024), 256, 0, stream>>>(X, embH, WiT, bsum, H);
  rnnB_k<<<32, 256, 0, stream>>>(h0, WhT, H, flags, xbuf);
}